// Round 1
// baseline (65.264 us; speedup 1.0000x reference)
//
#include <hip/hip_runtime.h>
#include <hip/hip_bf16.h>

// LinearMinimumBit: y = x @ dequant3bit(W)^T + bias
// x:[64,8192] f32, weight_q3:[4194304,6] int32 (byte values), weight_norm:[4194304] f32, bias:[8192] f32
// out:[64,8192] f32
//
// ws layout: [0, 1MB)   x converted to bf16  (64*8192*2)
//            [1MB, 9.4MB) K-slice partials [4][64][8192] f32

#define BATCH   64
#define IN_F    8192
#define OUT_F   8192
#define GPR_ROW (IN_F / 16)      // 512 groups per output row
#define KSLICES 4
#define BN      64
#define BK      64
#define K_SLICE (IN_F / KSLICES) // 2048
#define NT      (K_SLICE / BK)   // 32 K-tiles per slice

typedef __attribute__((ext_vector_type(8))) short bf16x8;
typedef __attribute__((ext_vector_type(4))) float f32x4;

__device__ __forceinline__ ushort f2bf(float f) {
  union { float f; unsigned u; } a; a.f = f;
  unsigned r = a.u + 0x7fffu + ((a.u >> 16) & 1u);
  return (ushort)(r >> 16);
}

// one 3-byte triplet -> 8 bf16 weights, w = a*(2v-7), a = norm/7
__device__ __forceinline__ void unpack_triplet(int b0, int b1, int b2, float a, ushort* o) {
  o[0] = f2bf(a * (float)(2 * ((b0 >> 5) & 7) - 7));
  o[1] = f2bf(a * (float)(2 * ((b0 >> 2) & 7) - 7));
  o[2] = f2bf(a * (float)(2 * (((b0 & 3) << 1) | ((b1 >> 7) & 1)) - 7));
  o[3] = f2bf(a * (float)(2 * ((b1 >> 4) & 7) - 7));
  o[4] = f2bf(a * (float)(2 * ((b1 >> 1) & 7) - 7));
  o[5] = f2bf(a * (float)(2 * (((b1 & 1) << 2) | ((b2 >> 6) & 3)) - 7));
  o[6] = f2bf(a * (float)(2 * ((b2 >> 3) & 7) - 7));
  o[7] = f2bf(a * (float)(2 * (b2 & 7) - 7));
}

__global__ void __launch_bounds__(256) xcvt_kernel(const float* __restrict__ x,
                                                   ushort* __restrict__ xb) {
  int i = blockIdx.x * 256 + threadIdx.x;  // float4 index, exactly 131072 launched
  float4 v = ((const float4*)x)[i];
  ushort4 o;
  o.x = f2bf(v.x); o.y = f2bf(v.y); o.z = f2bf(v.z); o.w = f2bf(v.w);
  ((ushort4*)xb)[i] = o;
}

__global__ void __launch_bounds__(256) gemm3b_kernel(const ushort* __restrict__ xb,
                                                     const int* __restrict__ wq,
                                                     const float* __restrict__ wnorm,
                                                     float* __restrict__ partial) {
  __shared__ ushort Bl[BN][BK + 8];  // +8 pad: break power-of-2 bank stride

  const int tid  = threadIdx.x;
  const int lane = tid & 63;
  const int wid  = tid >> 6;   // 4 waves
  const int wm   = wid >> 1;   // wave row (0..1) -> M 32-range
  const int wnn  = wid & 1;    // wave col (0..1) -> N 32-range
  const int n0   = blockIdx.x * BN;
  const int s    = blockIdx.y;
  const int kbase = s * K_SLICE;

  // staging assignment: thread -> one 16-weight group of the 64x64 B tile
  const int n_loc = tid >> 2;  // 0..63  (row of B tile = out feature)
  const int kk    = tid & 3;   // 0..3   (which 16-group along BK=64)
  const long grow = (long)(n0 + n_loc) * GPR_ROW + kk;

  f32x4 acc[2][2];
  #pragma unroll
  for (int m = 0; m < 2; ++m)
    #pragma unroll
    for (int n = 0; n < 2; ++n) acc[m][n] = (f32x4){0.f, 0.f, 0.f, 0.f};

  const int2* wq2 = (const int2*)wq;  // 6 ints per group = 3 int2, 8B-aligned
  long g = grow + (kbase >> 4);
  int2 p01 = wq2[g * 3 + 0];
  int2 p23 = wq2[g * 3 + 1];
  int2 p45 = wq2[g * 3 + 2];
  float nrm = wnorm[g];

  const int lrow = lane & 15;
  const int lk8  = (lane >> 4) * 8;

  for (int kt = 0; kt < NT; ++kt) {
    __syncthreads();  // previous tile's LDS reads complete
    {
      float a = nrm * (1.0f / 7.0f);
      union { ushort u[8]; bf16x8 v; } lo, hi;
      unpack_triplet(p01.x, p01.y, p23.x, a, lo.u);
      unpack_triplet(p23.y, p45.x, p45.y, a, hi.u);
      *(bf16x8*)&Bl[n_loc][kk * 16]     = lo.v;
      *(bf16x8*)&Bl[n_loc][kk * 16 + 8] = hi.v;
    }
    __syncthreads();  // B tile ready
    if (kt + 1 < NT) {  // prefetch next tile's packed bytes; latency hides under MFMA
      long g2 = grow + ((kbase + (kt + 1) * BK) >> 4);
      p01 = wq2[g2 * 3 + 0];
      p23 = wq2[g2 * 3 + 1];
      p45 = wq2[g2 * 3 + 2];
      nrm = wnorm[g2];
    }
    const int k0 = kbase + kt * BK;
    #pragma unroll
    for (int ks = 0; ks < 2; ++ks) {
      bf16x8 af[2], bfr[2];
      #pragma unroll
      for (int m = 0; m < 2; ++m)
        af[m] = *(const bf16x8*)&xb[(wm * 32 + m * 16 + lrow) * IN_F + k0 + ks * 32 + lk8];
      #pragma unroll
      for (int n = 0; n < 2; ++n)
        bfr[n] = *(const bf16x8*)&Bl[wnn * 32 + n * 16 + lrow][ks * 32 + lk8];
      #pragma unroll
      for (int m = 0; m < 2; ++m)
        #pragma unroll
        for (int n = 0; n < 2; ++n)
          acc[m][n] = __builtin_amdgcn_mfma_f32_16x16x32_bf16(af[m], bfr[n], acc[m][n], 0, 0, 0);
    }
  }

  // epilogue: C/D layout col=lane&15, row=(lane>>4)*4+r  (verified m89)
  float* pout = partial + (size_t)s * BATCH * OUT_F;
  #pragma unroll
  for (int m = 0; m < 2; ++m)
    #pragma unroll
    for (int n = 0; n < 2; ++n) {
      int col  = n0 + wnn * 32 + n * 16 + (lane & 15);
      int rowb = wm * 32 + m * 16 + (lane >> 4) * 4;
      #pragma unroll
      for (int r = 0; r < 4; ++r)
        pout[(size_t)(rowb + r) * OUT_F + col] = acc[m][n][r];
    }
}

__global__ void __launch_bounds__(256) reduce_kernel(const float* __restrict__ partial,
                                                     const float* __restrict__ bias,
                                                     float* __restrict__ out) {
  int i = blockIdx.x * 256 + threadIdx.x;  // float4 index over [64][8192], 131072 launched
  float4 a = ((const float4*)partial)[i];
  #pragma unroll
  for (int s2 = 1; s2 < KSLICES; ++s2) {
    float4 b = ((const float4*)partial)[i + s2 * (BATCH * OUT_F / 4)];
    a.x += b.x; a.y += b.y; a.z += b.z; a.w += b.w;
  }
  float4 bv = ((const float4*)bias)[i & (OUT_F / 4 - 1)];
  a.x += bv.x; a.y += bv.y; a.z += bv.z; a.w += bv.w;
  ((float4*)out)[i] = a;
}

extern "C" void kernel_launch(void* const* d_in, const int* in_sizes, int n_in,
                              void* d_out, int out_size, void* d_ws, size_t ws_size,
                              hipStream_t stream) {
  const float* x     = (const float*)d_in[0];
  const int*   wq    = (const int*)d_in[1];
  const float* wnorm = (const float*)d_in[2];
  const float* bias  = (const float*)d_in[3];
  float* out = (float*)d_out;

  ushort* xb      = (ushort*)d_ws;                                  // 1 MB
  float*  partial = (float*)((char*)d_ws + (size_t)BATCH * IN_F * 2);  // 8.4 MB

  // 1) x fp32 -> bf16
  hipLaunchKernelGGL(xcvt_kernel, dim3(BATCH * IN_F / 4 / 256), dim3(256), 0, stream, x, xb);
  // 2) K-sliced MFMA GEMM with in-register 3-bit dequant
  hipLaunchKernelGGL(gemm3b_kernel, dim3(OUT_F / BN, KSLICES), dim3(256), 0, stream,
                     xb, wq, wnorm, partial);
  // 3) reduce K-slices + bias
  hipLaunchKernelGGL(reduce_kernel, dim3(BATCH * OUT_F / 4 / 256), dim3(256), 0, stream,
                     partial, bias, out);
}

// Round 2
// 59.614 us; speedup vs baseline: 1.0948x; 1.0948x over previous
//
#include <hip/hip_runtime.h>
#include <hip/hip_bf16.h>

// LinearMinimumBit: y = x @ dequant3bit(W)^T + bias
// x:[64,8192] f32, weight_q3:[4194304,6] int32 (byte values), weight_norm:[4194304] f32,
// bias:[8192] f32 -> out:[64,8192] f32
//
// ws layout: [0, 1MB)  x as bf16; [1MB, 1MB+KS*2MB) K-slice partials [KS][64][8192] f32

#define BATCH   64
#define IN_F    8192
#define OUT_F   8192
#define GPR_ROW (IN_F / 16)   // 512 groups per output row
#define BN      64
#define BK      64

typedef __attribute__((ext_vector_type(8))) short bf16x8;
typedef __attribute__((ext_vector_type(4))) float f32x4;

__device__ __forceinline__ ushort f2bf(float f) {
  union { float f; unsigned u; } a; a.f = f;
  unsigned r = a.u + 0x7fffu + ((a.u >> 16) & 1u);
  return (ushort)(r >> 16);
}

// one 3-byte triplet -> 8 bf16 weights, w = v*c1 - c0  (c1=2*norm/7, c0=norm)
__device__ __forceinline__ void dq8(int b0, int b1, int b2, float c1, float c0,
                                    __hip_bfloat162* h) {
  int v0 = (b0 >> 5) & 7;
  int v1 = (b0 >> 2) & 7;
  int v2 = ((b0 & 3) << 1) | ((b1 >> 7) & 1);
  int v3 = (b1 >> 4) & 7;
  int v4 = (b1 >> 1) & 7;
  int v5 = ((b1 & 1) << 2) | ((b2 >> 6) & 3);
  int v6 = (b2 >> 3) & 7;
  int v7 = b2 & 7;
  float f0 = fmaf((float)v0, c1, -c0);
  float f1 = fmaf((float)v1, c1, -c0);
  float f2 = fmaf((float)v2, c1, -c0);
  float f3 = fmaf((float)v3, c1, -c0);
  float f4 = fmaf((float)v4, c1, -c0);
  float f5 = fmaf((float)v5, c1, -c0);
  float f6 = fmaf((float)v6, c1, -c0);
  float f7 = fmaf((float)v7, c1, -c0);
  h[0] = __float22bfloat162_rn(make_float2(f0, f1));
  h[1] = __float22bfloat162_rn(make_float2(f2, f3));
  h[2] = __float22bfloat162_rn(make_float2(f4, f5));
  h[3] = __float22bfloat162_rn(make_float2(f6, f7));
}

__global__ void __launch_bounds__(256) xcvt_kernel(const float* __restrict__ x,
                                                   ushort* __restrict__ xb) {
  int i = blockIdx.x * 256 + threadIdx.x;
  float4 v = ((const float4*)x)[i];
  ushort4 o;
  o.x = f2bf(v.x); o.y = f2bf(v.y); o.z = f2bf(v.z); o.w = f2bf(v.w);
  ((ushort4*)xb)[i] = o;
}

template <int KS>
__global__ void __launch_bounds__(256) gemm3b_kernel(const ushort* __restrict__ xb,
                                                     const int* __restrict__ wq,
                                                     const float* __restrict__ wnorm,
                                                     float* __restrict__ partial) {
  constexpr int K_SLICE = IN_F / KS;
  constexpr int NT = K_SLICE / BK;   // even for KS in {4,8}

  __shared__ ushort Bl[2][BN][BK + 8];

  const int tid  = threadIdx.x;
  const int lane = tid & 63;
  const int wid  = tid >> 6;
  const int wm   = wid >> 1;
  const int wnn  = wid & 1;
  const int n0   = blockIdx.x * BN;
  const int s    = blockIdx.y;
  const int kbase = s * K_SLICE;

  // staging: one 16-weight group per thread per tile
  const int n_loc = tid >> 2;   // 0..63
  const int kk    = tid & 3;    // 0..3
  const long gbase = (long)(n0 + n_loc) * GPR_ROW + (kbase >> 4) + kk;

  const int2* wq2 = (const int2*)wq;

  f32x4 acc[2][2];
  #pragma unroll
  for (int m = 0; m < 2; ++m)
    #pragma unroll
    for (int n = 0; n < 2; ++n) acc[m][n] = (f32x4){0.f, 0.f, 0.f, 0.f};

  const int lrow = lane & 15;
  const int lk8  = (lane >> 4) * 8;

  // two named pipeline slots (no runtime-indexed arrays -> no scratch)
  int2 a01, a23, a45; float an;
  int2 b01, b23, b45; float bn;

#define LOADG(P01, P23, P45, NRM, KT)                \
  do {                                               \
    long g2 = gbase + (long)(KT) * 4;                \
    P01 = wq2[g2 * 3 + 0];                           \
    P23 = wq2[g2 * 3 + 1];                           \
    P45 = wq2[g2 * 3 + 2];                           \
    NRM = wnorm[g2];                                 \
  } while (0)

#define DQ_STORE(P01, P23, P45, NRM, BUF)                        \
  do {                                                           \
    float c0 = NRM;                                              \
    float c1 = NRM * (2.0f / 7.0f);                              \
    union { __hip_bfloat162 h[4]; bf16x8 v; } lo_, hi_;          \
    dq8(P01.x, P01.y, P23.x, c1, c0, lo_.h);                     \
    dq8(P23.y, P45.x, P45.y, c1, c0, hi_.h);                     \
    *(bf16x8*)&Bl[BUF][n_loc][kk * 16]     = lo_.v;              \
    *(bf16x8*)&Bl[BUF][n_loc][kk * 16 + 8] = hi_.v;              \
  } while (0)

#define MFMA_TILE(BUF, KT)                                                             \
  do {                                                                                 \
    const int k0_ = kbase + (KT) * BK;                                                 \
    _Pragma("unroll")                                                                  \
    for (int ks = 0; ks < 2; ++ks) {                                                   \
      bf16x8 af[2], bfr[2];                                                            \
      _Pragma("unroll")                                                                \
      for (int m = 0; m < 2; ++m)                                                      \
        af[m] = *(const bf16x8*)&xb[(wm * 32 + m * 16 + lrow) * IN_F + k0_ + ks * 32 + lk8]; \
      _Pragma("unroll")                                                                \
      for (int n = 0; n < 2; ++n)                                                      \
        bfr[n] = *(const bf16x8*)&Bl[BUF][wnn * 32 + n * 16 + lrow][ks * 32 + lk8];    \
      _Pragma("unroll")                                                                \
      for (int m = 0; m < 2; ++m)                                                      \
        _Pragma("unroll")                                                              \
        for (int n = 0; n < 2; ++n)                                                    \
          acc[m][n] = __builtin_amdgcn_mfma_f32_16x16x32_bf16(af[m], bfr[n], acc[m][n], 0, 0, 0); \
    }                                                                                  \
  } while (0)

  LOADG(a01, a23, a45, an, 0);
  LOADG(b01, b23, b45, bn, 1);

  for (int kt = 0; kt < NT; kt += 2) {
    // even tile -> buffer 0
    DQ_STORE(a01, a23, a45, an, 0);
    if (kt + 2 < NT) LOADG(a01, a23, a45, an, kt + 2);
    __syncthreads();
    MFMA_TILE(0, kt);
    // odd tile -> buffer 1
    DQ_STORE(b01, b23, b45, bn, 1);
    if (kt + 3 < NT) LOADG(b01, b23, b45, bn, kt + 3);
    __syncthreads();
    MFMA_TILE(1, kt + 1);
  }

#undef LOADG
#undef DQ_STORE
#undef MFMA_TILE

  // epilogue: C/D layout col=lane&15, row=(lane>>4)*4+r (verified m89)
  float* pout = partial + (size_t)s * BATCH * OUT_F;
  #pragma unroll
  for (int m = 0; m < 2; ++m)
    #pragma unroll
    for (int n = 0; n < 2; ++n) {
      int col  = n0 + wnn * 32 + n * 16 + (lane & 15);
      int rowb = wm * 32 + m * 16 + (lane >> 4) * 4;
      #pragma unroll
      for (int r = 0; r < 4; ++r)
        pout[(size_t)(rowb + r) * OUT_F + col] = acc[m][n][r];
    }
}

template <int KS>
__global__ void __launch_bounds__(256) reduce_kernel(const float* __restrict__ partial,
                                                     const float* __restrict__ bias,
                                                     float* __restrict__ out) {
  int i = blockIdx.x * 256 + threadIdx.x;  // float4 index over [64][8192]
  float4 a = ((const float4*)partial)[i];
  #pragma unroll
  for (int s2 = 1; s2 < KS; ++s2) {
    float4 b = ((const float4*)partial)[i + s2 * (BATCH * OUT_F / 4)];
    a.x += b.x; a.y += b.y; a.z += b.z; a.w += b.w;
  }
  float4 bv = ((const float4*)bias)[i & (OUT_F / 4 - 1)];
  a.x += bv.x; a.y += bv.y; a.z += bv.z; a.w += bv.w;
  ((float4*)out)[i] = a;
}

extern "C" void kernel_launch(void* const* d_in, const int* in_sizes, int n_in,
                              void* d_out, int out_size, void* d_ws, size_t ws_size,
                              hipStream_t stream) {
  const float* x     = (const float*)d_in[0];
  const int*   wq    = (const int*)d_in[1];
  const float* wnorm = (const float*)d_in[2];
  const float* bias  = (const float*)d_in[3];
  float* out = (float*)d_out;

  const size_t xb_bytes = (size_t)BATCH * IN_F * 2;  // 1 MB
  ushort* xb      = (ushort*)d_ws;
  float*  partial = (float*)((char*)d_ws + xb_bytes);

  hipLaunchKernelGGL(xcvt_kernel, dim3(BATCH * IN_F / 4 / 256), dim3(256), 0, stream, x, xb);

  const size_t need8 = xb_bytes + (size_t)8 * BATCH * OUT_F * 4;  // ~17.8 MB
  if (ws_size >= need8) {
    hipLaunchKernelGGL((gemm3b_kernel<8>), dim3(OUT_F / BN, 8), dim3(256), 0, stream,
                       xb, wq, wnorm, partial);
    hipLaunchKernelGGL((reduce_kernel<8>), dim3(BATCH * OUT_F / 4 / 256), dim3(256), 0, stream,
                       partial, bias, out);
  } else {
    hipLaunchKernelGGL((gemm3b_kernel<4>), dim3(OUT_F / BN, 4), dim3(256), 0, stream,
                       xb, wq, wnorm, partial);
    hipLaunchKernelGGL((reduce_kernel<4>), dim3(BATCH * OUT_F / 4 / 256), dim3(256), 0, stream,
                       partial, bias, out);
  }
}